// Round 2
// baseline (1206.567 us; speedup 1.0000x reference)
//
#include <hip/hip_runtime.h>
#include <math.h>

#define NUMPIX 256
#define NUMBIN 367
#define NUMTHETA 360
#define NS 4
#define NT 367
#define NPIX2 (NUMPIX * NUMPIX)          // 65536
#define NRAYS_ALL (NUMTHETA * NUMBIN)    // 132120
#define NANG_SUB (NUMTHETA / NS)         // 90
#define NRAYS_SUB (NANG_SUB * NUMBIN)    // 33030

#define CDET 183.0f
#define CPIX 127.5f
#define TOFF 183.0f                      // (NT-1)/2
#define DEN_EPS 1e-6f
#define EPS_F 2.2204460492503131e-16f    // float64 eps
#define RES2_THRESH 1e-4f                // (0.01)^2
#define INV_DINV (1.0f / 90.0f)          // backproject(ones) == 90 exactly

// padded image: rows/cols -1..257 stored at +1; stride 260, 259 rows
#define SW 260
#define SH 259
#define PADN (SW * SH)                   // 67340

// ---- workspace layout (in floats) ----
#define OFF_COS  0
#define OFF_SIN  (OFF_COS + NUMTHETA)            // 360
#define OFF_MINV (OFF_SIN + NUMTHETA)            // 720
#define OFF_FK   (OFF_MINV + NRAYS_ALL)          // 132840
#define OFF_FPAD (OFF_FK + NPIX2)                // 198376
#define OFF_DIFF (OFF_FPAD + PADN)               // 265716
#define OFF_RES  (OFF_DIFF + NRAYS_SUB)          // 298746

// ---------------- trig setup ----------------
__global__ void setup_trig(float* __restrict__ cosA, float* __restrict__ sinA) {
    int a = blockIdx.x * blockDim.x + threadIdx.x;
    if (a < NUMTHETA) {
        float th = (float)((double)a * 0.017453292519943295);
        cosA[a] = (float)cos((double)th);
        sinA[a] = (float)sin((double)th);
    }
}

// ---------------- Minv (analytic, no loads) ----------------
// Minv(angle,bin) = max(sum_t u(x)*u(y), 1e-6), u = separable border-band weight.
__global__ __launch_bounds__(256)
void minv_kernel(float* __restrict__ minv,
                 const float* __restrict__ cosA,
                 const float* __restrict__ sinA) {
    const int wid = threadIdx.x >> 6, lane = threadIdx.x & 63;
    int ray = blockIdx.x * 4 + wid;               // grid 33030 -> 132120 exact
    int angle = ray / NUMBIN;
    int bin = ray - angle * NUMBIN;
    float ca = cosA[angle], sa = sinA[angle];
    float s = (float)bin - CDET;
    float acc = 0.0f;
    #pragma unroll
    for (int i = 0; i < 6; i++) {
        float tt = (float)(lane + 64 * i) - TOFF;   // t >= 367 contributes 0
        float x = fmaf(s, ca, fmaf(-tt, sa, CPIX));
        float y = fmaf(s, sa, fmaf(tt, ca, CPIX));
        float fx = floorf(x), fy = floorf(y);
        float wx = x - fx, wy = y - fy;
        int c0 = (int)fx, r0 = (int)fy;
        float ux = (((unsigned)c0 < 256u) ? (1.0f - wx) : 0.0f) +
                   (((unsigned)(c0 + 1) < 256u) ? wx : 0.0f);
        float uy = (((unsigned)r0 < 256u) ? (1.0f - wy) : 0.0f) +
                   (((unsigned)(r0 + 1) < 256u) ? wy : 0.0f);
        acc += ux * uy;
    }
    #pragma unroll
    for (int off = 32; off; off >>= 1) acc += __shfl_down(acc, off);
    if (lane == 0) minv[ray] = fmaxf(acc, DEN_EPS);
}

// ---------------- forward projection (padded image, unconditional loads) ----
// MODE 1: diffs[ai*NUMBIN+bin] = (sino - FP(img)) / Minv
// MODE 2: atomicAdd(out, sum((FP(img) - sino)^2))
template <int MODE>
__global__ __launch_bounds__(256)
void fp_kernel(const float* __restrict__ pad,
               const float* __restrict__ sino,
               const float* __restrict__ minv,
               float* __restrict__ out,
               const float* __restrict__ cosA,
               const float* __restrict__ sinA,
               int angleStart, int angleStride, int nRays) {
    const int wid = threadIdx.x >> 6, lane = threadIdx.x & 63;
    const int ray = blockIdx.x * 4 + wid;
    float d2 = 0.0f;
    if (MODE == 1 && ray >= nRays) return;
    if (ray < nRays) {
        int ai = ray / NUMBIN;
        int bin = ray - ai * NUMBIN;
        int angle = angleStart + ai * angleStride;
        float ca = cosA[angle], sa = sinA[angle];
        float s = (float)bin - CDET;
        float acc = 0.0f;
        #pragma unroll
        for (int i = 0; i < 6; i++) {
            float tt = (float)(lane + 64 * i) - TOFF;  // t >= 367 -> outside -> 0
            float x = fmaf(s, ca, fmaf(-tt, sa, CPIX));
            float y = fmaf(s, sa, fmaf(tt, ca, CPIX));
            // clamp into the zero-pad guard band; outside-image samples read 0s
            float xc = fminf(fmaxf(x, -1.0f), 256.0f);
            float yc = fminf(fmaxf(y, -1.0f), 256.0f);
            float fx = floorf(xc), fy = floorf(yc);
            float wx = xc - fx, wy = yc - fy;
            int c0 = (int)fx, r0 = (int)fy;
            const float* p = pad + (r0 + 1) * SW + (c0 + 1);
            float v00 = p[0], v01 = p[1], v10 = p[SW], v11 = p[SW + 1];
            float top = fmaf(wx, v01 - v00, v00);
            float bot = fmaf(wx, v11 - v10, v10);
            acc += fmaf(wy, bot - top, top);
        }
        #pragma unroll
        for (int off = 32; off; off >>= 1) acc += __shfl_down(acc, off);
        if (lane == 0) {
            if (MODE == 1) {
                out[ray] = (sino[angle * NUMBIN + bin] - acc) /
                           minv[angle * NUMBIN + bin];
            } else {
                float d = acc - sino[angle * NUMBIN + bin];
                d2 = d * d;
            }
        }
    }
    if (MODE == 2) {
        __shared__ float part[4];
        if (lane == 0) part[wid] = d2;
        __syncthreads();
        if (threadIdx.x == 0)
            atomicAdd(out, part[0] + part[1] + part[2] + part[3]);
    }
}

// ---------------- backprojection + SART update ----------------
// 64 pixels/block, 4 waves split the 90-angle loop, LDS reduce.
// bounds checks dropped: sd in [2.7, 363.3] always. Dinv == 90.
__global__ __launch_bounds__(256)
void bp_update_kernel(float* __restrict__ fk,
                      float* __restrict__ fpad,
                      const float* __restrict__ g,      // diffs [90,367]
                      const float* __restrict__ cosA,
                      const float* __restrict__ sinA,
                      int j, int doClamp) {
    __shared__ float part[4][64];
    const int tx = threadIdx.x & 63;
    const int ty = threadIdx.x >> 6;
    int p = blockIdx.x * 64 + tx;
    int px = p & (NUMPIX - 1), py = p >> 8;
    float X = (float)px - CPIX, Y = (float)py - CPIX;
    float acc = 0.0f;
    for (int i = ty; i < NANG_SUB; i += 4) {
        int angle = j + NS * i;
        float ca = cosA[angle], sa = sinA[angle];
        float sd = fmaf(X, ca, fmaf(Y, sa, CDET));
        float f0 = floorf(sd);
        float w = sd - f0;
        int i0 = (int)f0;
        const float* gp = g + i * NUMBIN + i0;
        float v0 = gp[0], v1 = gp[1];
        acc += fmaf(w, v1 - v0, v0);
    }
    part[ty][tx] = acc;
    __syncthreads();
    if (ty == 0) {
        float s = part[0][tx] + part[1][tx] + part[2][tx] + part[3][tx];
        float bp = (fabsf(s) > 1000.0f) ? 0.0f : s;
        float v = fk[p] + bp * INV_DINV;
        if (doClamp) v = fmaxf(v, EPS_F);
        fk[p] = v;
        fpad[(py + 1) * SW + (px + 1)] = v;
    }
}

// ---------------- misc ----------------
__global__ void init_kernel(float* __restrict__ fpad, float* __restrict__ fk,
                            float* __restrict__ fcur,
                            const float* __restrict__ f0) {
    int idx = blockIdx.x * blockDim.x + threadIdx.x;
    if (idx >= PADN) return;
    int r = idx / SW, c = idx - r * SW;
    float v = 0.0f;
    if (r >= 1 && r <= 256 && c >= 1 && c <= 256) {
        int p = (r - 1) * NUMPIX + (c - 1);
        v = f0[p];
        fk[p] = v;
        fcur[p] = v;
    }
    fpad[idx] = v;
}

__global__ void zero_kernel(float* __restrict__ r) { *r = 0.0f; }

__global__ void select_kernel(float* __restrict__ fcur, float* __restrict__ fk,
                              float* __restrict__ fpad,
                              const float* __restrict__ res2) {
    int p = blockIdx.x * blockDim.x + threadIdx.x;
    int px = p & (NUMPIX - 1), py = p >> 8;
    bool upd = (*res2 > RES2_THRESH);   // res = sqrt(res2) > 0.01
    float v = upd ? fk[p] : fcur[p];
    fcur[p] = v;
    fk[p] = v;
    fpad[(py + 1) * SW + (px + 1)] = v;
}

extern "C" void kernel_launch(void* const* d_in, const int* in_sizes, int n_in,
                              void* d_out, int out_size, void* d_ws, size_t ws_size,
                              hipStream_t stream) {
    const float* f0 = (const float*)d_in[0];     // [256,256]
    const float* sino = (const float*)d_in[1];   // [360,367]
    float* fcur = (float*)d_out;                 // [256,256] output "f"
    float* ws = (float*)d_ws;

    float* cosA = ws + OFF_COS;
    float* sinA = ws + OFF_SIN;
    float* minv = ws + OFF_MINV;   // [360,367] indexed by global angle
    float* fk   = ws + OFF_FK;     // [256,256]
    float* fpad = ws + OFF_FPAD;   // [259 rows x 260 stride] zero-padded fk
    float* diff = ws + OFF_DIFF;   // [90,367]
    float* res2 = ws + OFF_RES;    // scalar

    setup_trig<<<6, 64, 0, stream>>>(cosA, sinA);

    // Minv over all 360 angles (analytic, no memory traffic)
    minv_kernel<<<NRAYS_ALL / 4, 256, 0, stream>>>(minv, cosA, sinA);

    init_kernel<<<(PADN + 255) / 256, 256, 0, stream>>>(fpad, fk, fcur, f0);

    for (int iter = 0; iter < 2; iter++) {
        for (int j = 0; j < NS; j++) {
            fp_kernel<1><<<(NRAYS_SUB + 3) / 4, 256, 0, stream>>>(
                fpad, sino, minv, diff, cosA, sinA, j, NS, NRAYS_SUB);
            bp_update_kernel<<<NPIX2 / 64, 256, 0, stream>>>(
                fk, fpad, diff, cosA, sinA, j, (j == NS - 1) ? 1 : 0);
        }
        zero_kernel<<<1, 1, 0, stream>>>(res2);
        fp_kernel<2><<<NRAYS_ALL / 4, 256, 0, stream>>>(
            fpad, sino, nullptr, res2, cosA, sinA, 0, 1, NRAYS_ALL);
        select_kernel<<<NPIX2 / 256, 256, 0, stream>>>(fcur, fk, fpad, res2);
    }
}

// Round 3
// 474.233 us; speedup vs baseline: 2.5442x; 2.5442x over previous
//
#include <hip/hip_runtime.h>
#include <math.h>

#define NUMPIX 256
#define NUMBIN 367
#define NUMTHETA 360
#define NS 4
#define NT 367
#define NPIX2 (NUMPIX * NUMPIX)          // 65536
#define NRAYS_ALL (NUMTHETA * NUMBIN)    // 132120
#define NANG_SUB (NUMTHETA / NS)         // 90
#define NRAYS_SUB (NANG_SUB * NUMBIN)    // 33030

#define CDET 183.0f
#define CPIX 127.5f
#define TOFF 183.0f                      // (NT-1)/2
#define DEN_EPS 1e-6f
#define EPS_F 2.2204460492503131e-16f    // float64 eps
#define RES2_THRESH 1e-4f                // (0.01)^2
#define INV_DINV (1.0f / 90.0f)          // backproject(ones) == 90 exactly

// padded image: rows/cols -1..257 stored at +1; stride 260, 259 rows
#define SW 260
#define SH 259
#define PADN (SW * SH)                   // 67340

// ---- workspace layout (in floats) ----
#define OFF_COS   0
#define OFF_SIN   (OFF_COS + NUMTHETA)           // 360
#define OFF_MINV  (OFF_SIN + NUMTHETA)           // 720
#define OFF_FK    (OFF_MINV + NRAYS_ALL)         // 132840
#define OFF_FPAD  (OFF_FK + NPIX2)               // 198376
#define OFF_FPADT (OFF_FPAD + PADN)              // 265716
#define OFF_DIFF  (OFF_FPADT + PADN)             // 333056 (reused as residual partials)
#define OFF_RES   (OFF_DIFF + NRAYS_SUB)         // 366086

// ---------------- trig setup ----------------
__global__ void setup_trig(float* __restrict__ cosA, float* __restrict__ sinA) {
    int a = blockIdx.x * blockDim.x + threadIdx.x;
    if (a < NUMTHETA) {
        float th = (float)((double)a * 0.017453292519943295);
        cosA[a] = (float)cos((double)th);
        sinA[a] = (float)sin((double)th);
    }
}

// ---------------- Minv (analytic, no loads) ----------------
__global__ __launch_bounds__(256)
void minv_kernel(float* __restrict__ minv,
                 const float* __restrict__ cosA,
                 const float* __restrict__ sinA) {
    const int wid = threadIdx.x >> 6, lane = threadIdx.x & 63;
    int ray = blockIdx.x * 4 + wid;               // grid 33030 -> 132120 exact
    int angle = ray / NUMBIN;
    int bin = ray - angle * NUMBIN;
    float ca = cosA[angle], sa = sinA[angle];
    float s = (float)bin - CDET;
    float acc = 0.0f;
    #pragma unroll
    for (int i = 0; i < 6; i++) {
        float tt = (float)(lane + 64 * i) - TOFF;   // t >= 367 contributes 0
        float x = fmaf(s, ca, fmaf(-tt, sa, CPIX));
        float y = fmaf(s, sa, fmaf(tt, ca, CPIX));
        float fx = floorf(x), fy = floorf(y);
        float wx = x - fx, wy = y - fy;
        int c0 = (int)fx, r0 = (int)fy;
        float ux = (((unsigned)c0 < 256u) ? (1.0f - wx) : 0.0f) +
                   (((unsigned)(c0 + 1) < 256u) ? wx : 0.0f);
        float uy = (((unsigned)r0 < 256u) ? (1.0f - wy) : 0.0f) +
                   (((unsigned)(r0 + 1) < 256u) ? wy : 0.0f);
        acc += ux * uy;
    }
    #pragma unroll
    for (int off = 32; off; off >>= 1) acc += __shfl_down(acc, off);
    if (lane == 0) minv[ray] = fmaxf(acc, DEN_EPS);
}

// ---------------- forward projection (dual-layout padded image) ----------
// Per angle, sample the layout (normal or transposed) in which the lane-fast
// ray motion runs along the contiguous axis: row-change rate = min(|ca|,|sa|).
// MODE 1: diffs[ray] = (sino - FP) / Minv
// MODE 2: out[blockIdx.x] = block partial of sum((FP - sino)^2)
template <int MODE>
__global__ __launch_bounds__(256)
void fp_kernel(const float* __restrict__ pad,
               const float* __restrict__ padT,
               const float* __restrict__ sino,
               const float* __restrict__ minv,
               float* __restrict__ out,
               const float* __restrict__ cosA,
               const float* __restrict__ sinA,
               int angleStart, int angleStride, int nRays) {
    const int wid = threadIdx.x >> 6, lane = threadIdx.x & 63;
    const int ray = blockIdx.x * 4 + wid;
    float d2 = 0.0f;
    if (MODE == 1 && ray >= nRays) return;
    {
        int ai = ray / NUMBIN;
        int bin = ray - ai * NUMBIN;
        int angle = angleStart + ai * angleStride;
        float ca = cosA[angle], sa = sinA[angle];
        bool useT = fabsf(ca) > fabsf(sa);        // wave-uniform
        const float* img = useT ? padT : pad;
        float s = (float)bin - CDET;
        float acc = 0.0f;
        #pragma unroll
        for (int i = 0; i < 6; i++) {
            float tt = (float)(lane + 64 * i) - TOFF;  // t >= 367 -> outside -> 0
            float x = fmaf(s, ca, fmaf(-tt, sa, CPIX));
            float y = fmaf(s, sa, fmaf(tt, ca, CPIX));
            float xx = useT ? y : x;              // contiguous-axis coordinate
            float yy = useT ? x : y;              // strided-axis coordinate
            // clamp into the zero-pad guard band; outside samples read 0s
            xx = fminf(fmaxf(xx, -1.0f), 256.0f);
            yy = fminf(fmaxf(yy, -1.0f), 256.0f);
            float fx = floorf(xx), fy = floorf(yy);
            float wx = xx - fx, wy = yy - fy;
            int c0 = (int)fx, r0 = (int)fy;
            const float* p = img + (r0 + 1) * SW + (c0 + 1);
            float v00 = p[0], v01 = p[1], v10 = p[SW], v11 = p[SW + 1];
            float top = fmaf(wx, v01 - v00, v00);
            float bot = fmaf(wx, v11 - v10, v10);
            acc += fmaf(wy, bot - top, top);
        }
        #pragma unroll
        for (int off = 32; off; off >>= 1) acc += __shfl_down(acc, off);
        if (lane == 0) {
            if (MODE == 1) {
                out[ray] = (sino[angle * NUMBIN + bin] - acc) /
                           minv[angle * NUMBIN + bin];
            } else {
                float d = acc - sino[angle * NUMBIN + bin];
                d2 = d * d;
            }
        }
    }
    if (MODE == 2) {
        __shared__ float part[4];
        if (lane == 0) part[wid] = d2;
        __syncthreads();
        if (threadIdx.x == 0)
            out[blockIdx.x] = part[0] + part[1] + part[2] + part[3];
    }
}

// single-block reduction of residual partials -> res2
__global__ __launch_bounds__(1024)
void reduce_res2(const float* __restrict__ part, float* __restrict__ res2, int n) {
    __shared__ float buf[16];
    float a = 0.0f;
    for (int i = threadIdx.x; i < n; i += 1024) a += part[i];
    #pragma unroll
    for (int off = 32; off; off >>= 1) a += __shfl_down(a, off);
    if ((threadIdx.x & 63) == 0) buf[threadIdx.x >> 6] = a;
    __syncthreads();
    if (threadIdx.x == 0) {
        float s = 0.0f;
        #pragma unroll
        for (int i = 0; i < 16; i++) s += buf[i];
        *res2 = s;
    }
}

// ---------------- backprojection + SART update ----------------
__global__ __launch_bounds__(256)
void bp_update_kernel(float* __restrict__ fk,
                      float* __restrict__ fpad,
                      float* __restrict__ fpadT,
                      const float* __restrict__ g,      // diffs [90,367]
                      const float* __restrict__ cosA,
                      const float* __restrict__ sinA,
                      int j, int doClamp) {
    __shared__ float part[4][64];
    const int tx = threadIdx.x & 63;
    const int ty = threadIdx.x >> 6;
    int p = blockIdx.x * 64 + tx;
    int px = p & (NUMPIX - 1), py = p >> 8;
    float X = (float)px - CPIX, Y = (float)py - CPIX;
    float acc = 0.0f;
    for (int i = ty; i < NANG_SUB; i += 4) {
        int angle = j + NS * i;
        float ca = cosA[angle], sa = sinA[angle];
        float sd = fmaf(X, ca, fmaf(Y, sa, CDET));   // always in [2.7, 363.3]
        float f0 = floorf(sd);
        float w = sd - f0;
        int i0 = (int)f0;
        const float* gp = g + i * NUMBIN + i0;
        float v0 = gp[0], v1 = gp[1];
        acc += fmaf(w, v1 - v0, v0);
    }
    part[ty][tx] = acc;
    __syncthreads();
    if (ty == 0) {
        float s = part[0][tx] + part[1][tx] + part[2][tx] + part[3][tx];
        float bp = (fabsf(s) > 1000.0f) ? 0.0f : s;
        float v = fk[p] + bp * INV_DINV;
        if (doClamp) v = fmaxf(v, EPS_F);
        fk[p] = v;
        fpad[(py + 1) * SW + (px + 1)] = v;
        fpadT[(px + 1) * SW + (py + 1)] = v;
    }
}

// ---------------- misc ----------------
__global__ void init_kernel(float* __restrict__ fpad, float* __restrict__ fpadT,
                            float* __restrict__ fk, float* __restrict__ fcur,
                            const float* __restrict__ f0) {
    int idx = blockIdx.x * blockDim.x + threadIdx.x;
    if (idx >= PADN) return;
    int r = idx / SW, c = idx - r * SW;
    float v = 0.0f, vT = 0.0f;
    if (r >= 1 && r <= 256 && c >= 1 && c <= 256) {
        v = f0[(r - 1) * NUMPIX + (c - 1)];
        vT = f0[(c - 1) * NUMPIX + (r - 1)];
        int p = (r - 1) * NUMPIX + (c - 1);
        fk[p] = v;
        fcur[p] = v;
    }
    fpad[idx] = v;
    fpadT[idx] = vT;
}

__global__ void select_kernel(float* __restrict__ fcur, float* __restrict__ fk,
                              float* __restrict__ fpad, float* __restrict__ fpadT,
                              const float* __restrict__ res2) {
    int p = blockIdx.x * blockDim.x + threadIdx.x;
    int px = p & (NUMPIX - 1), py = p >> 8;
    bool upd = (*res2 > RES2_THRESH);   // res = sqrt(res2) > 0.01
    float v = upd ? fk[p] : fcur[p];
    fcur[p] = v;
    fk[p] = v;
    fpad[(py + 1) * SW + (px + 1)] = v;
    fpadT[(px + 1) * SW + (py + 1)] = v;
}

extern "C" void kernel_launch(void* const* d_in, const int* in_sizes, int n_in,
                              void* d_out, int out_size, void* d_ws, size_t ws_size,
                              hipStream_t stream) {
    const float* f0 = (const float*)d_in[0];     // [256,256]
    const float* sino = (const float*)d_in[1];   // [360,367]
    float* fcur = (float*)d_out;                 // [256,256] output "f"
    float* ws = (float*)d_ws;

    float* cosA  = ws + OFF_COS;
    float* sinA  = ws + OFF_SIN;
    float* minv  = ws + OFF_MINV;   // [360,367] indexed by global angle
    float* fk    = ws + OFF_FK;     // [256,256]
    float* fpad  = ws + OFF_FPAD;   // [259 x 260] zero-padded fk
    float* fpadT = ws + OFF_FPADT;  // transposed zero-padded fk
    float* diff  = ws + OFF_DIFF;   // [90,367]; reused as residual partials
    float* res2  = ws + OFF_RES;    // scalar

    setup_trig<<<6, 64, 0, stream>>>(cosA, sinA);

    minv_kernel<<<NRAYS_ALL / 4, 256, 0, stream>>>(minv, cosA, sinA);

    init_kernel<<<(PADN + 255) / 256, 256, 0, stream>>>(fpad, fpadT, fk, fcur, f0);

    for (int iter = 0; iter < 2; iter++) {
        for (int j = 0; j < NS; j++) {
            fp_kernel<1><<<(NRAYS_SUB + 3) / 4, 256, 0, stream>>>(
                fpad, fpadT, sino, minv, diff, cosA, sinA, j, NS, NRAYS_SUB);
            bp_update_kernel<<<NPIX2 / 64, 256, 0, stream>>>(
                fk, fpad, fpadT, diff, cosA, sinA, j, (j == NS - 1) ? 1 : 0);
        }
        // residual: per-block partials into diff (idle here), then reduce
        fp_kernel<2><<<NRAYS_ALL / 4, 256, 0, stream>>>(
            fpad, fpadT, sino, nullptr, diff, cosA, sinA, 0, 1, NRAYS_ALL);
        reduce_res2<<<1, 1024, 0, stream>>>(diff, res2, NRAYS_ALL / 4);
        select_kernel<<<NPIX2 / 256, 256, 0, stream>>>(fcur, fk, fpad, fpadT, res2);
    }
}

// Round 4
// 403.647 us; speedup vs baseline: 2.9892x; 1.1749x over previous
//
#include <hip/hip_runtime.h>
#include <math.h>

#define NUMPIX 256
#define NUMBIN 367
#define NUMTHETA 360
#define NS 4
#define NT 367
#define NPIX2 (NUMPIX * NUMPIX)          // 65536
#define NRAYS_ALL (NUMTHETA * NUMBIN)    // 132120
#define NANG_SUB (NUMTHETA / NS)         // 90
#define NRAYS_SUB (NANG_SUB * NUMBIN)    // 33030

#define CDET 183.0f
#define CPIX 127.5f
#define TOFF 183.0f                      // (NT-1)/2
#define DEN_EPS 1e-6f
#define EPS_F 2.2204460492503131e-16f    // float64 eps
#define RES2_THRESH 1e-4f                // (0.01)^2
#define INV_DINV (1.0f / 90.0f)          // backproject(ones) == 90 exactly

// padded image: rows/cols -1..257 stored at +1; stride 260, 259 rows
#define SW 260
#define SH 259
#define PADN (SW * SH)                   // 67340

#define RES_BLOCKS 4096                  // MODE-2 grid (grid-stride)

// ---- workspace layout (in floats) ----
#define OFF_COS   0
#define OFF_SIN   (OFF_COS + NUMTHETA)           // 360
#define OFF_MINV  (OFF_SIN + NUMTHETA)           // 720
#define OFF_FK    (OFF_MINV + NRAYS_ALL)         // 132840
#define OFF_FPAD  (OFF_FK + NPIX2)               // 198376
#define OFF_FPADT (OFF_FPAD + PADN)              // 265716
#define OFF_DIFF  (OFF_FPADT + PADN)             // 333056 (also residual partials)
#define OFF_RES   (OFF_DIFF + NRAYS_SUB)         // 366086

// ---------------- trig setup ----------------
__global__ void setup_trig(float* __restrict__ cosA, float* __restrict__ sinA) {
    int a = blockIdx.x * blockDim.x + threadIdx.x;
    if (a < NUMTHETA) {
        float th = (float)((double)a * 0.017453292519943295);
        cosA[a] = (float)cos((double)th);
        sinA[a] = (float)sin((double)th);
    }
}

// t-interval (in tt units, tt = t - 183) where the ray can touch the image.
// coord(tt) = c0 + rate*tt kept within [-2, 257]: 1px slack each side, so any
// excluded sample is exactly zero (reads only pad zeros / masked weights).
__device__ __forceinline__ void clip_axis(float c0, float rate,
                                          float& lo, float& hi) {
    if (fabsf(rate) > 1e-6f) {
        float inv = 1.0f / rate;
        float a = (-2.0f - c0) * inv;
        float b = (257.0f - c0) * inv;
        lo = fmaxf(lo, fminf(a, b));
        hi = fminf(hi, fmaxf(a, b));
    } else if (c0 <= -2.0f || c0 >= 257.0f) {
        lo = 1e9f; hi = -1e9f;
    }
}

// returns chunk count; sets itlo (first t index)
__device__ __forceinline__ int ray_chunks(float x0, float y0, float ca, float sa,
                                          int& itlo) {
    float lo = -1e9f, hi = 1e9f;
    clip_axis(x0, -sa, lo, hi);
    clip_axis(y0,  ca, lo, hi);
    if (hi < lo) { itlo = 0; return 0; }
    int a = (int)floorf(lo + TOFF) - 1; if (a < 0) a = 0;
    int b = (int)ceilf(hi + TOFF) + 1;  if (b > NT - 1) b = NT - 1;
    itlo = a;
    if (b < a) return 0;
    return (b - a + 64) >> 6;
}

// ---------------- Minv (analytic, no loads, t-clipped) ----------------
__global__ __launch_bounds__(256)
void minv_kernel(float* __restrict__ minv,
                 const float* __restrict__ cosA,
                 const float* __restrict__ sinA) {
    const int wid = threadIdx.x >> 6, lane = threadIdx.x & 63;
    int ray = blockIdx.x * 4 + wid;               // grid 33030 -> 132120 exact
    int angle = ray / NUMBIN;
    int bin = ray - angle * NUMBIN;
    float ca = cosA[angle], sa = sinA[angle];
    float s = (float)bin - CDET;
    float x0 = fmaf(s, ca, CPIX);                 // x(tt) = x0 - tt*sa
    float y0 = fmaf(s, sa, CPIX);                 // y(tt) = y0 + tt*ca
    int itlo, nc = ray_chunks(x0, y0, ca, sa, itlo);
    float acc = 0.0f;
    for (int ic = 0; ic < nc; ic++) {
        float tt = (float)(itlo + (ic << 6) + lane) - TOFF;
        float x = fmaf(-tt, sa, x0);
        float y = fmaf(tt, ca, y0);
        float fx = floorf(x), fy = floorf(y);
        float wx = x - fx, wy = y - fy;
        int c0 = (int)fx, r0 = (int)fy;
        float ux = (((unsigned)c0 < 256u) ? (1.0f - wx) : 0.0f) +
                   (((unsigned)(c0 + 1) < 256u) ? wx : 0.0f);
        float uy = (((unsigned)r0 < 256u) ? (1.0f - wy) : 0.0f) +
                   (((unsigned)(r0 + 1) < 256u) ? wy : 0.0f);
        acc += ux * uy;
    }
    #pragma unroll
    for (int off = 32; off; off >>= 1) acc += __shfl_down(acc, off);
    if (lane == 0) minv[ray] = fmaxf(acc, DEN_EPS);
}

// ---------------- forward projection (dual layout + t-clipped) ----------
// Per ray pick the layout in which the fast coordinate runs contiguous:
//   fast rate = max(|ca|,|sa|), strided rate = min(|ca|,|sa|).
// MODE 1: one ray/wave; diffs[ray] = (sino - FP) / Minv
// MODE 2: grid-stride; out[blockIdx.x] = block partial of sum((FP - sino)^2)
template <int MODE>
__global__ __launch_bounds__(256)
void fp_kernel(const float* __restrict__ pad,
               const float* __restrict__ padT,
               const float* __restrict__ sino,
               const float* __restrict__ minv,
               float* __restrict__ out,
               const float* __restrict__ cosA,
               const float* __restrict__ sinA,
               int angleStart, int angleStride, int nRays) {
    const int wid = threadIdx.x >> 6, lane = threadIdx.x & 63;
    float wacc = 0.0f;

    int ray = blockIdx.x * 4 + wid;
    if (MODE == 1 && ray >= nRays) return;
    const int rayStep = (MODE == 2) ? RES_BLOCKS * 4 : NRAYS_ALL;  // MODE1: once

    for (; ray < nRays; ray += rayStep) {
        int ai = ray / NUMBIN;
        int bin = ray - ai * NUMBIN;
        int angle = angleStart + ai * angleStride;
        float ca = cosA[angle], sa = sinA[angle];
        float s = (float)bin - CDET;
        float x0 = fmaf(s, ca, CPIX);             // x(tt) = x0 - tt*sa
        float y0 = fmaf(s, sa, CPIX);             // y(tt) = y0 + tt*ca
        int itlo, nc = ray_chunks(x0, y0, ca, sa, itlo);

        bool useT = fabsf(ca) > fabsf(sa);        // wave-uniform
        const float* img = (useT ? padT : pad) + (SW + 1);
        float u0 = useT ? y0 : x0, du = useT ? ca : -sa;   // fast (contiguous)
        float v0 = useT ? x0 : y0, dv = useT ? -sa : ca;   // slow (strided)

        float acc = 0.0f;
        for (int ic = 0; ic < nc; ic++) {
            float tt = (float)(itlo + (ic << 6) + lane) - TOFF;
            float u = fmaf(tt, du, u0);
            float v = fmaf(tt, dv, v0);
            u = fminf(fmaxf(u, -1.0f), 256.0f);   // clamp into zero guard band
            v = fminf(fmaxf(v, -1.0f), 256.0f);
            float fu = floorf(u), fv = floorf(v);
            float wu = u - fu, wv = v - fv;
            int cu = (int)fu, rv = (int)fv;
            const float* p = img + rv * SW + cu;
            float v00 = p[0], v01 = p[1], v10 = p[SW], v11 = p[SW + 1];
            float top = fmaf(wu, v01 - v00, v00);
            float bot = fmaf(wu, v11 - v10, v10);
            acc += fmaf(wv, bot - top, top);
        }
        #pragma unroll
        for (int off = 32; off; off >>= 1) acc += __shfl_down(acc, off);
        if (lane == 0) {
            if (MODE == 1) {
                out[ray] = (sino[angle * NUMBIN + bin] - acc) /
                           minv[angle * NUMBIN + bin];
            } else {
                float d = acc - sino[angle * NUMBIN + bin];
                wacc += d * d;
            }
        }
        if (MODE == 1) break;
    }
    if (MODE == 2) {
        __shared__ float part[4];
        if (lane == 0) part[wid] = wacc;
        __syncthreads();
        if (threadIdx.x == 0)
            out[blockIdx.x] = part[0] + part[1] + part[2] + part[3];
    }
}

// single-block reduction of residual partials -> res2
__global__ __launch_bounds__(1024)
void reduce_res2(const float* __restrict__ part, float* __restrict__ res2, int n) {
    __shared__ float buf[16];
    float a = 0.0f;
    for (int i = threadIdx.x; i < n; i += 1024) a += part[i];
    #pragma unroll
    for (int off = 32; off; off >>= 1) a += __shfl_down(a, off);
    if ((threadIdx.x & 63) == 0) buf[threadIdx.x >> 6] = a;
    __syncthreads();
    if (threadIdx.x == 0) {
        float s = 0.0f;
        #pragma unroll
        for (int i = 0; i < 16; i++) s += buf[i];
        *res2 = s;
    }
}

// ---------------- backprojection + SART update ----------------
__global__ __launch_bounds__(256)
void bp_update_kernel(float* __restrict__ fk,
                      float* __restrict__ fpad,
                      float* __restrict__ fpadT,
                      const float* __restrict__ g,      // diffs [90,367]
                      const float* __restrict__ cosA,
                      const float* __restrict__ sinA,
                      int j, int doClamp) {
    __shared__ float part[4][64];
    const int tx = threadIdx.x & 63;
    const int ty = threadIdx.x >> 6;
    int p = blockIdx.x * 64 + tx;
    int px = p & (NUMPIX - 1), py = p >> 8;
    float X = (float)px - CPIX, Y = (float)py - CPIX;
    float acc = 0.0f;
    for (int i = ty; i < NANG_SUB; i += 4) {
        int angle = j + NS * i;
        float ca = cosA[angle], sa = sinA[angle];
        float sd = fmaf(X, ca, fmaf(Y, sa, CDET));   // always in [2.7, 363.3]
        float f0 = floorf(sd);
        float w = sd - f0;
        int i0 = (int)f0;
        const float* gp = g + i * NUMBIN + i0;
        float v0 = gp[0], v1 = gp[1];
        acc += fmaf(w, v1 - v0, v0);
    }
    part[ty][tx] = acc;
    __syncthreads();
    if (ty == 0) {
        float s = part[0][tx] + part[1][tx] + part[2][tx] + part[3][tx];
        float bp = (fabsf(s) > 1000.0f) ? 0.0f : s;
        float v = fk[p] + bp * INV_DINV;
        if (doClamp) v = fmaxf(v, EPS_F);
        fk[p] = v;
        fpad[(py + 1) * SW + (px + 1)] = v;
        fpadT[(px + 1) * SW + (py + 1)] = v;
    }
}

// ---------------- misc ----------------
__global__ void init_kernel(float* __restrict__ fpad, float* __restrict__ fpadT,
                            float* __restrict__ fk, float* __restrict__ fcur,
                            const float* __restrict__ f0) {
    int idx = blockIdx.x * blockDim.x + threadIdx.x;
    if (idx >= PADN) return;
    int r = idx / SW, c = idx - r * SW;
    float v = 0.0f, vT = 0.0f;
    if (r >= 1 && r <= 256 && c >= 1 && c <= 256) {
        v = f0[(r - 1) * NUMPIX + (c - 1)];
        vT = f0[(c - 1) * NUMPIX + (r - 1)];
        int p = (r - 1) * NUMPIX + (c - 1);
        fk[p] = v;
        fcur[p] = v;
    }
    fpad[idx] = v;
    fpadT[idx] = vT;
}

__global__ void select_kernel(float* __restrict__ fcur, float* __restrict__ fk,
                              float* __restrict__ fpad, float* __restrict__ fpadT,
                              const float* __restrict__ res2) {
    int p = blockIdx.x * blockDim.x + threadIdx.x;
    int px = p & (NUMPIX - 1), py = p >> 8;
    bool upd = (*res2 > RES2_THRESH);   // res = sqrt(res2) > 0.01
    float v = upd ? fk[p] : fcur[p];
    fcur[p] = v;
    fk[p] = v;
    fpad[(py + 1) * SW + (px + 1)] = v;
    fpadT[(px + 1) * SW + (py + 1)] = v;
}

extern "C" void kernel_launch(void* const* d_in, const int* in_sizes, int n_in,
                              void* d_out, int out_size, void* d_ws, size_t ws_size,
                              hipStream_t stream) {
    const float* f0 = (const float*)d_in[0];     // [256,256]
    const float* sino = (const float*)d_in[1];   // [360,367]
    float* fcur = (float*)d_out;                 // [256,256] output "f"
    float* ws = (float*)d_ws;

    float* cosA  = ws + OFF_COS;
    float* sinA  = ws + OFF_SIN;
    float* minv  = ws + OFF_MINV;   // [360,367] indexed by global angle
    float* fk    = ws + OFF_FK;     // [256,256]
    float* fpad  = ws + OFF_FPAD;   // [259 x 260] zero-padded fk
    float* fpadT = ws + OFF_FPADT;  // transposed zero-padded fk
    float* diff  = ws + OFF_DIFF;   // [90,367]; reused as residual partials
    float* res2  = ws + OFF_RES;    // scalar

    setup_trig<<<6, 64, 0, stream>>>(cosA, sinA);

    minv_kernel<<<NRAYS_ALL / 4, 256, 0, stream>>>(minv, cosA, sinA);

    init_kernel<<<(PADN + 255) / 256, 256, 0, stream>>>(fpad, fpadT, fk, fcur, f0);

    for (int iter = 0; iter < 2; iter++) {
        for (int j = 0; j < NS; j++) {
            fp_kernel<1><<<(NRAYS_SUB + 3) / 4, 256, 0, stream>>>(
                fpad, fpadT, sino, minv, diff, cosA, sinA, j, NS, NRAYS_SUB);
            bp_update_kernel<<<NPIX2 / 64, 256, 0, stream>>>(
                fk, fpad, fpadT, diff, cosA, sinA, j, (j == NS - 1) ? 1 : 0);
        }
        // residual: grid-stride partials into diff (idle here), then reduce
        fp_kernel<2><<<RES_BLOCKS, 256, 0, stream>>>(
            fpad, fpadT, sino, nullptr, diff, cosA, sinA, 0, 1, NRAYS_ALL);
        reduce_res2<<<1, 1024, 0, stream>>>(diff, res2, RES_BLOCKS);
        select_kernel<<<NPIX2 / 256, 256, 0, stream>>>(fcur, fk, fpad, fpadT, res2);
    }
}

// Round 5
// 402.423 us; speedup vs baseline: 2.9983x; 1.0030x over previous
//
#include <hip/hip_runtime.h>
#include <math.h>

#define NUMPIX 256
#define NUMBIN 367
#define NUMTHETA 360
#define NS 4
#define NT 367
#define NPIX2 (NUMPIX * NUMPIX)          // 65536
#define NRAYS_ALL (NUMTHETA * NUMBIN)    // 132120
#define NANG_SUB (NUMTHETA / NS)         // 90
#define NRAYS_SUB (NANG_SUB * NUMBIN)    // 33030

#define CDET 183.0f
#define CPIX 127.5f
#define TOFF 183.0f                      // (NT-1)/2
#define DEN_EPS 1e-6f
#define EPS_F 2.2204460492503131e-16f    // float64 eps
#define RES2_THRESH 1e-4f                // (0.01)^2
#define INV_DINV (1.0f / 90.0f)          // backproject(ones) == 90 exactly

// padded image: rows/cols -1..257 stored at +1; stride 260, 259 rows
#define SW 260
#define SH 259
#define PADN (SW * SH)                   // 67340

#define RES_BLOCKS 4096                  // MODE-2 grid (grid-stride)

// 8-byte vector with only 4-byte alignment guarantee (pairs at arbitrary col)
typedef float f2u __attribute__((ext_vector_type(2), aligned(4)));

// ---- workspace layout (in floats) ----
#define OFF_COS   0
#define OFF_SIN   (OFF_COS + NUMTHETA)           // 360
#define OFF_MINV  (OFF_SIN + NUMTHETA)           // 720
#define OFF_FK    (OFF_MINV + NRAYS_ALL)         // 132840
#define OFF_FPAD  (OFF_FK + NPIX2)               // 198376
#define OFF_FPADT (OFF_FPAD + PADN)              // 265716
#define OFF_DIFF  (OFF_FPADT + PADN)             // 333056 (also residual partials)
#define OFF_RES   (OFF_DIFF + NRAYS_SUB)         // 366086

// ---------------- trig setup ----------------
__global__ void setup_trig(float* __restrict__ cosA, float* __restrict__ sinA) {
    int a = blockIdx.x * blockDim.x + threadIdx.x;
    if (a < NUMTHETA) {
        float th = (float)((double)a * 0.017453292519943295);
        cosA[a] = (float)cos((double)th);
        sinA[a] = (float)sin((double)th);
    }
}

// t-interval (in tt units) where the ray can touch the image; 1px slack so
// fp rounding of endpoints only adds exactly-zero samples.
__device__ __forceinline__ void clip_axis(float c0, float rate,
                                          float& lo, float& hi) {
    if (fabsf(rate) > 1e-6f) {
        float inv = 1.0f / rate;
        float a = (-2.0f - c0) * inv;
        float b = (257.0f - c0) * inv;
        lo = fmaxf(lo, fminf(a, b));
        hi = fminf(hi, fmaxf(a, b));
    } else if (c0 <= -2.0f || c0 >= 257.0f) {
        lo = 1e9f; hi = -1e9f;
    }
}

__device__ __forceinline__ int ray_chunks(float x0, float y0, float ca, float sa,
                                          int& itlo) {
    float lo = -1e9f, hi = 1e9f;
    clip_axis(x0, -sa, lo, hi);
    clip_axis(y0,  ca, lo, hi);
    if (hi < lo) { itlo = 0; return 0; }
    int a = (int)floorf(lo + TOFF) - 1; if (a < 0) a = 0;
    int b = (int)ceilf(hi + TOFF) + 1;  if (b > NT - 1) b = NT - 1;
    itlo = a;
    if (b < a) return 0;
    return (b - a + 64) >> 6;
}

// ---------------- Minv (analytic, no loads, t-clipped) ----------------
__global__ __launch_bounds__(256)
void minv_kernel(float* __restrict__ minv,
                 const float* __restrict__ cosA,
                 const float* __restrict__ sinA) {
    const int wid = threadIdx.x >> 6, lane = threadIdx.x & 63;
    int ray = blockIdx.x * 4 + wid;               // grid 33030 -> 132120 exact
    int angle = ray / NUMBIN;
    int bin = ray - angle * NUMBIN;
    float ca = cosA[angle], sa = sinA[angle];
    float s = (float)bin - CDET;
    float x0 = fmaf(s, ca, CPIX);                 // x(tt) = x0 - tt*sa
    float y0 = fmaf(s, sa, CPIX);                 // y(tt) = y0 + tt*ca
    int itlo, nc = ray_chunks(x0, y0, ca, sa, itlo);
    float tt0 = (float)(itlo + lane) - TOFF;
    float x = fmaf(-tt0, sa, x0);
    float y = fmaf(tt0, ca, y0);
    const float dx64 = -sa * 64.0f, dy64 = ca * 64.0f;
    float acc = 0.0f;
    for (int ic = 0; ic < nc; ic++) {
        float fx = floorf(x), fy = floorf(y);
        float wx = x - fx, wy = y - fy;
        int c0 = (int)fx, r0 = (int)fy;
        float ux = (((unsigned)c0 < 256u) ? (1.0f - wx) : 0.0f) +
                   (((unsigned)(c0 + 1) < 256u) ? wx : 0.0f);
        float uy = (((unsigned)r0 < 256u) ? (1.0f - wy) : 0.0f) +
                   (((unsigned)(r0 + 1) < 256u) ? wy : 0.0f);
        acc += ux * uy;
        x += dx64; y += dy64;
    }
    #pragma unroll
    for (int off = 32; off; off >>= 1) acc += __shfl_down(acc, off);
    if (lane == 0) minv[ray] = fmaxf(acc, DEN_EPS);
}

// ---------------- forward projection (dual layout + t-clip + pair loads) --
// MODE 1: one ray/wave; diffs[ray] = (sino - FP) / Minv
// MODE 2: grid-stride; out[blockIdx.x] = block partial of sum((FP - sino)^2)
template <int MODE>
__global__ __launch_bounds__(256)
void fp_kernel(const float* __restrict__ pad,
               const float* __restrict__ padT,
               const float* __restrict__ sino,
               const float* __restrict__ minv,
               float* __restrict__ out,
               const float* __restrict__ cosA,
               const float* __restrict__ sinA,
               int angleStart, int angleStride, int nRays) {
    const int wid = threadIdx.x >> 6, lane = threadIdx.x & 63;
    float wacc = 0.0f;

    int ray = blockIdx.x * 4 + wid;
    if (MODE == 1 && ray >= nRays) return;
    const int rayStep = (MODE == 2) ? RES_BLOCKS * 4 : NRAYS_ALL;  // MODE1: once

    for (; ray < nRays; ray += rayStep) {
        int ai = ray / NUMBIN;
        int bin = ray - ai * NUMBIN;
        int angle = angleStart + ai * angleStride;
        float ca = cosA[angle], sa = sinA[angle];
        float s = (float)bin - CDET;
        float x0 = fmaf(s, ca, CPIX);             // x(tt) = x0 - tt*sa
        float y0 = fmaf(s, sa, CPIX);             // y(tt) = y0 + tt*ca
        int itlo, nc = ray_chunks(x0, y0, ca, sa, itlo);

        bool useT = fabsf(ca) > fabsf(sa);        // wave-uniform
        const float* img = (useT ? padT : pad) + (SW + 1);
        float u0 = useT ? y0 : x0, du = useT ? ca : -sa;   // fast (contiguous)
        float v0 = useT ? x0 : y0, dv = useT ? -sa : ca;   // slow (strided)

        float tt0 = (float)(itlo + lane) - TOFF;
        float u = fmaf(tt0, du, u0);
        float v = fmaf(tt0, dv, v0);
        const float du64 = du * 64.0f, dv64 = dv * 64.0f;

        float acc = 0.0f;
        for (int ic = 0; ic < nc; ic++) {
            float uc = fminf(fmaxf(u, -1.0f), 256.0f);   // into zero guard band
            float vc = fminf(fmaxf(v, -1.0f), 256.0f);
            float fu = floorf(uc), fv = floorf(vc);
            float wu = uc - fu, wv = vc - fv;
            int cu = (int)fu, rv = (int)fv;
            const float* p = img + rv * SW + cu;
            f2u t0 = *(const f2u*)p;          // v00, v01 (8B load, 4B aligned)
            f2u t1 = *(const f2u*)(p + SW);   // v10, v11
            float top = fmaf(wu, t0.y - t0.x, t0.x);
            float bot = fmaf(wu, t1.y - t1.x, t1.x);
            acc += fmaf(wv, bot - top, top);
            u += du64; v += dv64;
        }
        #pragma unroll
        for (int off = 32; off; off >>= 1) acc += __shfl_down(acc, off);
        if (lane == 0) {
            if (MODE == 1) {
                out[ray] = (sino[angle * NUMBIN + bin] - acc) /
                           minv[angle * NUMBIN + bin];
            } else {
                float d = acc - sino[angle * NUMBIN + bin];
                wacc += d * d;
            }
        }
        if (MODE == 1) break;
    }
    if (MODE == 2) {
        __shared__ float part[4];
        if (lane == 0) part[wid] = wacc;
        __syncthreads();
        if (threadIdx.x == 0)
            out[blockIdx.x] = part[0] + part[1] + part[2] + part[3];
    }
}

// single-block reduction of residual partials -> res2
__global__ __launch_bounds__(1024)
void reduce_res2(const float* __restrict__ part, float* __restrict__ res2, int n) {
    __shared__ float buf[16];
    float a = 0.0f;
    for (int i = threadIdx.x; i < n; i += 1024) a += part[i];
    #pragma unroll
    for (int off = 32; off; off >>= 1) a += __shfl_down(a, off);
    if ((threadIdx.x & 63) == 0) buf[threadIdx.x >> 6] = a;
    __syncthreads();
    if (threadIdx.x == 0) {
        float s = 0.0f;
        #pragma unroll
        for (int i = 0; i < 16; i++) s += buf[i];
        *res2 = s;
    }
}

// ---------------- backprojection + SART update ----------------
__global__ __launch_bounds__(256)
void bp_update_kernel(float* __restrict__ fk,
                      float* __restrict__ fpad,
                      float* __restrict__ fpadT,
                      const float* __restrict__ g,      // diffs [90,367]
                      const float* __restrict__ cosA,
                      const float* __restrict__ sinA,
                      int j, int doClamp) {
    __shared__ float part[4][64];
    const int tx = threadIdx.x & 63;
    const int ty = threadIdx.x >> 6;
    int p = blockIdx.x * 64 + tx;
    int px = p & (NUMPIX - 1), py = p >> 8;
    float X = (float)px - CPIX, Y = (float)py - CPIX;
    float acc = 0.0f;
    for (int i = ty; i < NANG_SUB; i += 4) {
        int angle = j + NS * i;
        float ca = cosA[angle], sa = sinA[angle];
        float sd = fmaf(X, ca, fmaf(Y, sa, CDET));   // always in [2.7, 363.3]
        float f0 = floorf(sd);
        float w = sd - f0;
        int i0 = (int)f0;
        f2u gv = *(const f2u*)(g + i * NUMBIN + i0);
        acc += fmaf(w, gv.y - gv.x, gv.x);
    }
    part[ty][tx] = acc;
    __syncthreads();
    if (ty == 0) {
        float s = part[0][tx] + part[1][tx] + part[2][tx] + part[3][tx];
        float bp = (fabsf(s) > 1000.0f) ? 0.0f : s;
        float v = fk[p] + bp * INV_DINV;
        if (doClamp) v = fmaxf(v, EPS_F);
        fk[p] = v;
        fpad[(py + 1) * SW + (px + 1)] = v;
        fpadT[(px + 1) * SW + (py + 1)] = v;
    }
}

// ---------------- misc ----------------
__global__ void init_kernel(float* __restrict__ fpad, float* __restrict__ fpadT,
                            float* __restrict__ fk, float* __restrict__ fcur,
                            const float* __restrict__ f0) {
    int idx = blockIdx.x * blockDim.x + threadIdx.x;
    if (idx >= PADN) return;
    int r = idx / SW, c = idx - r * SW;
    float v = 0.0f, vT = 0.0f;
    if (r >= 1 && r <= 256 && c >= 1 && c <= 256) {
        v = f0[(r - 1) * NUMPIX + (c - 1)];
        vT = f0[(c - 1) * NUMPIX + (r - 1)];
        int p = (r - 1) * NUMPIX + (c - 1);
        fk[p] = v;
        fcur[p] = v;
    }
    fpad[idx] = v;
    fpadT[idx] = vT;
}

__global__ void select_kernel(float* __restrict__ fcur, float* __restrict__ fk,
                              float* __restrict__ fpad, float* __restrict__ fpadT,
                              const float* __restrict__ res2) {
    int p = blockIdx.x * blockDim.x + threadIdx.x;
    int px = p & (NUMPIX - 1), py = p >> 8;
    bool upd = (*res2 > RES2_THRESH);   // res = sqrt(res2) > 0.01
    float v = upd ? fk[p] : fcur[p];
    fcur[p] = v;
    fk[p] = v;
    fpad[(py + 1) * SW + (px + 1)] = v;
    fpadT[(px + 1) * SW + (py + 1)] = v;
}

extern "C" void kernel_launch(void* const* d_in, const int* in_sizes, int n_in,
                              void* d_out, int out_size, void* d_ws, size_t ws_size,
                              hipStream_t stream) {
    const float* f0 = (const float*)d_in[0];     // [256,256]
    const float* sino = (const float*)d_in[1];   // [360,367]
    float* fcur = (float*)d_out;                 // [256,256] output "f"
    float* ws = (float*)d_ws;

    float* cosA  = ws + OFF_COS;
    float* sinA  = ws + OFF_SIN;
    float* minv  = ws + OFF_MINV;   // [360,367] indexed by global angle
    float* fk    = ws + OFF_FK;     // [256,256]
    float* fpad  = ws + OFF_FPAD;   // [259 x 260] zero-padded fk
    float* fpadT = ws + OFF_FPADT;  // transposed zero-padded fk
    float* diff  = ws + OFF_DIFF;   // [90,367]; reused as residual partials
    float* res2  = ws + OFF_RES;    // scalar

    setup_trig<<<6, 64, 0, stream>>>(cosA, sinA);

    minv_kernel<<<NRAYS_ALL / 4, 256, 0, stream>>>(minv, cosA, sinA);

    init_kernel<<<(PADN + 255) / 256, 256, 0, stream>>>(fpad, fpadT, fk, fcur, f0);

    for (int iter = 0; iter < 2; iter++) {
        for (int j = 0; j < NS; j++) {
            fp_kernel<1><<<(NRAYS_SUB + 3) / 4, 256, 0, stream>>>(
                fpad, fpadT, sino, minv, diff, cosA, sinA, j, NS, NRAYS_SUB);
            bp_update_kernel<<<NPIX2 / 64, 256, 0, stream>>>(
                fk, fpad, fpadT, diff, cosA, sinA, j, (j == NS - 1) ? 1 : 0);
        }
        // residual: grid-stride partials into diff (idle here), then reduce
        fp_kernel<2><<<RES_BLOCKS, 256, 0, stream>>>(
            fpad, fpadT, sino, nullptr, diff, cosA, sinA, 0, 1, NRAYS_ALL);
        reduce_res2<<<1, 1024, 0, stream>>>(diff, res2, RES_BLOCKS);
        select_kernel<<<NPIX2 / 256, 256, 0, stream>>>(fcur, fk, fpad, fpadT, res2);
    }
}